// Round 19
// baseline (35.161 us; speedup 1.0000x reference)
//
#include <hip/hip_runtime.h>
#include <hip/hip_bf16.h>

// CosSim2D (K=3, same-pad, C=32 -> F=32) on MI355X.
// Round 19: r12/r18 schedule at DOUBLE tile (16x32) to amortize per-block
// fixed latency (the only untried lever that avoids the spill wall).
//   - halo 18x34, two 40960B chunk-half buffers = 81920B LDS = exactly
//     2 blk/CU (8 waves). (256,2) -> 256-VGPR cap, ~190 live: cannot spill.
//   - wave computes 4 output rows (acc[4], 72 MFMAs); psum[6]/xinv[4].
//   - split-wait: vmcnt(10) after half0 -> compute h0 under half1's flight.
//   - keeps: DMA staging, XCD map, fused cvt+sumsq, NT stores, fast path.

#define H_ 224
#define W_ 224
#define C_ 32
#define F_ 32

#define NSTEP 18   // K = 288 = 18 * 16
#define TROWS 16   // output rows per block
#define HROWS 18   // staged halo rows (16 + 2)
#define HCOLS 34   // staged halo cols (32 + 2)
#define NPIX (HROWS * HCOLS)   // 612 pixels
#define HGRAN (NPIX * 4)       // 2448 16B granules per chunk-half
#define HPAD 2560              // 10 * 256 slots (pad slots -> zpool)

typedef __bf16 bf16_t;
typedef bf16_t bf16x8 __attribute__((ext_vector_type(8)));
typedef float f32x16 __attribute__((ext_vector_type(16)));

#define WFRAG_BYTES (NSTEP * 64 * 8 * 2)  // 18432 B

__device__ __forceinline__ void dma16(const void* gp, void* lp) {
  __builtin_amdgcn_global_load_lds(
      (const __attribute__((address_space(1))) void*)gp,
      (__attribute__((address_space(3))) void*)lp, 16, 0, 0);
}

// ---------------- prep (6 blocks): w-norm, exponents, B-frags, zero pool ----
__global__ __launch_bounds__(256) void cos2d_prep(
    const float* __restrict__ w, const float* __restrict__ p,
    const float* __restrict__ q, bf16_t* __restrict__ wfrag,
    float* __restrict__ winv, float* __restrict__ ef,
    float* __restrict__ zpool) {
  const int tid = threadIdx.x;
  if (blockIdx.x == 0) {
    __shared__ float part[8][32];
    const int f = tid & 31, kg = tid >> 5;
    float s = 0.f;
#pragma unroll
    for (int i = 0; i < 36; ++i) {
      const float v = w[(kg + 8 * i) * F_ + f];
      s += v * v;
    }
    part[kg][f] = s;
    zpool[tid] = 0.f;     // 1KB zero pool for OOB/pad DMA sources
    __syncthreads();
    if (tid < 32) {
      float t = 0.f;
#pragma unroll
      for (int g = 0; g < 8; ++g) t += part[g][tid];
      const float qt = q[0] * q[0] * 0.1f;
      winv[tid] = 1.f / (sqrtf(fmaxf(t, 1e-12f)) + qt);
      ef[tid] = p[tid] * p[tid] * 0.01f;
    }
  } else {
    // B-fragment layout for mfma_f32_32x32x16_bf16:
    //   lane l holds col f = l&31, k = s2*16 + (l>>5)*8 + e  (e = 0..7).
    const int t = (blockIdx.x - 1) * 256 + tid;
    if (t < NSTEP * 64) {
      const int s2 = t >> 6, l = t & 63;
      const int ff = l & 31;
      union { bf16_t v[8]; uint4 u; } tv;
#pragma unroll
      for (int e = 0; e < 8; ++e) {
        const int kk = s2 * 16 + ((l >> 5) << 3) + e;
        tv.v[e] = (bf16_t)w[kk * F_ + ff];
      }
      *(uint4*)(wfrag + (size_t)t * 8) = tv.u;
    }
  }
}

// ---------------- main ------------------------------------------------------
__global__ __launch_bounds__(256, 2) void cos2d_main(
    const float* __restrict__ img, const bf16_t* __restrict__ wfrag,
    const float* __restrict__ winv, const float* __restrict__ ef,
    const float* __restrict__ q, const float* __restrict__ zpool,
    float* __restrict__ out) {
  // Two chunk-half regions of HPAD granules. Within half h, pixel p's chunk
  // c (c>>2 == h) lives at granule h*HPAD + p*4 + ((c&3) ^ ((p>>1)&3))
  // -> 8 consecutive pixels at fixed c cover all 8 bank-groups.
  __shared__ __align__(16) float xt[2 * HPAD * 4];  // 81920 B -> 2 blk/CU

  const int tid = threadIdx.x;
  const int lane = tid & 63;
  const int wv = tid >> 6;
  const int lp = lane & 31;
  const int hi2 = (lane >> 5) * 2;   // chunk offset within half from lane-half

  // XCD-bijective mapping: image b == XCD (bid&7); tl walks tiles per image.
  const int bid = blockIdx.x;
  const int b  = bid & 7;
  const int tl = bid >> 3;           // 0..97
  const int tw = tl % 7, th = tl / 7;
  const int h0 = th * TROWS, w0 = tw * 32;

  const float qt = q[0] * q[0] * 0.1f;
  const float efv = ef[lp];
  const float wnv = winv[lp];
  const bool allfast = __all(__builtin_fabsf(efv - 1.0f) < 1e-6f);

  // ---- preload all 18 B-fragments (overlap the DMA batch)
  bf16x8 bfrag[NSTEP];
  const bf16x8* wf4 = (const bf16x8*)wfrag;
#pragma unroll
  for (int s2 = 0; s2 < NSTEP; ++s2) bfrag[s2] = wf4[s2 * 64 + lane];

  // ---- DMA staging: iters 0-9 = chunk-half 0, iters 10-19 = chunk-half 1.
  // Exactly 20 DMA per thread (pad/OOB slots pull zeros from zpool).
#pragma unroll
  for (int k = 0; k < 20; ++k) {
    const int s = k * 256 + tid;
    const int half = k >= 10;
    const int u = s - half * HPAD;         // granule within half
    float* lb = &xt[(size_t)(k * 256 + wv * 64) * 4];  // wave-uniform base
    const int uc = u < HGRAN ? u : 0;
    const int pp = uc >> 2;
    const int c  = half * 4 + ((uc & 3) ^ ((pp >> 1) & 3));
    const int rr = pp / HCOLS, cc = pp - rr * HCOLS;
    const int hh = h0 - 1 + rr, wc = w0 - 1 + cc;
    const bool live = (u < HGRAN) & ((unsigned)hh < H_) & ((unsigned)wc < W_);
    const float* src = live
        ? img + ((size_t)(b * H_ + hh) * W_ + wc) * C_ + c * 4
        : zpool + lane * 4;
    dma16(src, lb);
  }

  const int mr0 = wv * 4;  // this wave's 4 output rows (tile-relative)

  f32x16 acc[4];
#pragma unroll
  for (int t = 0; t < 4; ++t)
#pragma unroll
    for (int i = 0; i < 16; ++i) acc[t][i] = 0.f;
  float psum[6] = {0.f, 0.f, 0.f, 0.f, 0.f, 0.f};

  // ---- split-wait pipeline over chunk halves
#pragma unroll
  for (int h = 0; h < 2; ++h) {
    if (h == 0) {
      // drain bfrag + half0 (issued before half1); keep half1's 10 in flight
      asm volatile("s_waitcnt vmcnt(10)" ::: "memory");
    } else {
      asm volatile("s_waitcnt vmcnt(0)" ::: "memory");
    }
    __builtin_amdgcn_sched_barrier(0);
    __builtin_amdgcn_s_barrier();      // all waves' half-h DMAs retired
    __builtin_amdgcn_sched_barrier(0);

    const int hbase = h * (HPAD * 4);  // float offset of half region
#pragma unroll
    for (int dx = 0; dx < 3; ++dx) {
      bf16x8 af[6];
#pragma unroll
      for (int r = 0; r < 6; ++r) {
        const int p = (mr0 + r) * HCOLS + lp + dx;
        const int pj = (p >> 1) & 3;
        const int g0 = p * 4 + (hi2 ^ pj);
        const int g1 = p * 4 + ((hi2 + 1) ^ pj);
        const float4 f0 = *(const float4*)&xt[(size_t)(hbase + g0 * 4)];
        const float4 f1 = *(const float4*)&xt[(size_t)(hbase + g1 * 4)];
        psum[r] += f0.x * f0.x + f0.y * f0.y + f0.z * f0.z + f0.w * f0.w +
                   f1.x * f1.x + f1.y * f1.y + f1.z * f1.z + f1.w * f1.w;
        bf16x8 a;
        a[0] = (bf16_t)f0.x; a[1] = (bf16_t)f0.y;
        a[2] = (bf16_t)f0.z; a[3] = (bf16_t)f0.w;
        a[4] = (bf16_t)f1.x; a[5] = (bf16_t)f1.y;
        a[6] = (bf16_t)f1.z; a[7] = (bf16_t)f1.w;
        af[r] = a;
      }
#pragma unroll
      for (int dy = 0; dy < 3; ++dy) {
        const bf16x8 bf = bfrag[2 * (dy * 3 + dx) + h];
#pragma unroll
        for (int t = 0; t < 4; ++t)
          acc[t] = __builtin_amdgcn_mfma_f32_32x32x16_bf16(af[dy + t], bf,
                                                           acc[t], 0, 0, 0);
      }
    }
  }

  // x-norm from fused sums: lane and lane^32 hold complementary 16 channels.
#pragma unroll
  for (int r = 0; r < 6; ++r) psum[r] += __shfl_xor(psum[r], 32);
  float xinv[4];
#pragma unroll
  for (int t = 0; t < 4; ++t)
    xinv[t] = 1.f / (sqrtf(fmaxf(psum[t] + psum[t + 1] + psum[t + 2],
                                 1e-12f)) + qt);

  // epilogue: C/D col = lane&31 (filter), row = (j&3)+8*(j>>2)+4*(lane>>5).
#pragma unroll
  for (int t = 0; t < 4; ++t) {
    const int obase = (b * H_ + h0 + mr0 + t) * W_ + w0;
    if (allfast) {
#pragma unroll
      for (int jj = 0; jj < 16; ++jj) {
        const int row = (jj & 3) + 8 * (jj >> 2) + 4 * (lane >> 5);
        const float xi = __shfl(xinv[t], row);
        const float sim = acc[t][jj] * xi * wnv;
        const float r = copysignf(fabsf(sim) + 1e-12f, sim);  // |x|^1 path
        __builtin_nontemporal_store(r, &out[(size_t)(obase + row) * F_ + lp]);
      }
    } else {
#pragma unroll
      for (int jj = 0; jj < 16; ++jj) {
        const int row = (jj & 3) + 8 * (jj >> 2) + 4 * (lane >> 5);
        const float xi = __shfl(xinv[t], row);
        const float sim = acc[t][jj] * xi * wnv;
        const float ps = fabsf(sim) + 1e-12f;
        float r = exp2f(efv * __log2f(ps));
        r = copysignf(r, sim);
        __builtin_nontemporal_store(r, &out[(size_t)(obase + row) * F_ + lp]);
      }
    }
  }
}

// ---------------- launch ----------------------------------------------------
extern "C" void kernel_launch(void* const* d_in, const int* in_sizes, int n_in,
                              void* d_out, int out_size, void* d_ws, size_t ws_size,
                              hipStream_t stream) {
  const float* img = (const float*)d_in[0];
  const float* w   = (const float*)d_in[1];
  const float* p   = (const float*)d_in[2];
  const float* q   = (const float*)d_in[3];

  bf16_t* wfrag = (bf16_t*)d_ws;
  float*  winv  = (float*)((char*)d_ws + WFRAG_BYTES);
  float*  ef    = winv + 64;
  float*  zpool = ef + 64;   // 256 floats = 1KB zeros

  cos2d_prep<<<6, 256, 0, stream>>>(w, p, q, wfrag, winv, ef, zpool);
  // 784 blocks: image = bid&7 (== XCD), 14x7 tiles of 16x32 per image.
  cos2d_main<<<784, 256, 0, stream>>>(img, wfrag, winv, ef, q, zpool,
                                      (float*)d_out);
}

// Round 20
// 30.957 us; speedup vs baseline: 1.1358x; 1.1358x over previous
//
#include <hip/hip_runtime.h>
#include <hip/hip_bf16.h>

// CosSim2D (K=3, same-pad, C=32 -> F=32) on MI355X.
// Round 20 (FINAL): revert to round-18 — the measured optimum (30.8us).
//   Axis scan complete:
//   - tile: 8x32 @3blk/CU (30.8) beats 16x32 @2blk/CU (35.2, r19)
//   - occupancy: 12 waves/CU optimal (8: 35.2 r19; 16: unreachable without
//     spill r13-r17; 20: 35.9 r3)
//   - schedule: split-half counted vmcnt (30.8) beats plain barrier (32.7
//     r10) and deeper pipelines (spill, 78-99us r13/r14/r16/r17)
//   - staging: global_load_lds DMA beats VGPR round-trip (34.5 r7)
//   Structure: fp32 halo tile DMA'd in two chunk-halves (vmcnt(6) after
//   half0 -> compute h0 under half1's flight), bank-swizzled LDS, fused
//   bf16-cvt + x-norm sumsq in the K-loop, 18 preloaded B-frags,
//   XCD-bijective tile map, NT stores, exp==1 guarded fast path.

#define H_ 224
#define W_ 224
#define C_ 32
#define F_ 32

#define NSTEP 18   // K = 288 = 18 * 16
#define HROWS 10   // staged halo rows (8 + 2)
#define HCOLS 34   // staged halo cols (32 + 2)
#define NPIX (HROWS * HCOLS)   // 340 pixels
#define HGRAN (NPIX * 4)       // 1360 16B granules per chunk-half
#define HPAD 1536              // 6 * 256: padded half (pad slots -> zpool)

typedef __bf16 bf16_t;
typedef bf16_t bf16x8 __attribute__((ext_vector_type(8)));
typedef float f32x16 __attribute__((ext_vector_type(16)));

#define WFRAG_BYTES (NSTEP * 64 * 8 * 2)  // 18432 B

__device__ __forceinline__ void dma16(const void* gp, void* lp) {
  __builtin_amdgcn_global_load_lds(
      (const __attribute__((address_space(1))) void*)gp,
      (__attribute__((address_space(3))) void*)lp, 16, 0, 0);
}

// ---------------- prep (6 blocks): w-norm, exponents, B-frags, zero pool ----
__global__ __launch_bounds__(256) void cos2d_prep(
    const float* __restrict__ w, const float* __restrict__ p,
    const float* __restrict__ q, bf16_t* __restrict__ wfrag,
    float* __restrict__ winv, float* __restrict__ ef,
    float* __restrict__ zpool) {
  const int tid = threadIdx.x;
  if (blockIdx.x == 0) {
    __shared__ float part[8][32];
    const int f = tid & 31, kg = tid >> 5;
    float s = 0.f;
#pragma unroll
    for (int i = 0; i < 36; ++i) {
      const float v = w[(kg + 8 * i) * F_ + f];
      s += v * v;
    }
    part[kg][f] = s;
    zpool[tid] = 0.f;     // 1KB zero pool for OOB/pad DMA sources
    __syncthreads();
    if (tid < 32) {
      float t = 0.f;
#pragma unroll
      for (int g = 0; g < 8; ++g) t += part[g][tid];
      const float qt = q[0] * q[0] * 0.1f;
      winv[tid] = 1.f / (sqrtf(fmaxf(t, 1e-12f)) + qt);
      ef[tid] = p[tid] * p[tid] * 0.01f;
    }
  } else {
    // B-fragment layout for mfma_f32_32x32x16_bf16:
    //   lane l holds col f = l&31, k = s2*16 + (l>>5)*8 + e  (e = 0..7).
    const int t = (blockIdx.x - 1) * 256 + tid;
    if (t < NSTEP * 64) {
      const int s2 = t >> 6, l = t & 63;
      const int ff = l & 31;
      union { bf16_t v[8]; uint4 u; } tv;
#pragma unroll
      for (int e = 0; e < 8; ++e) {
        const int kk = s2 * 16 + ((l >> 5) << 3) + e;
        tv.v[e] = (bf16_t)w[kk * F_ + ff];
      }
      *(uint4*)(wfrag + (size_t)t * 8) = tv.u;
    }
  }
}

// ---------------- main ------------------------------------------------------
__global__ __launch_bounds__(256, 3) void cos2d_main(
    const float* __restrict__ img, const bf16_t* __restrict__ wfrag,
    const float* __restrict__ winv, const float* __restrict__ ef,
    const float* __restrict__ q, const float* __restrict__ zpool,
    float* __restrict__ out) {
  // Two chunk-half regions of HPAD granules each. Within half h, pixel p's
  // chunk c (c>>2 == h) lives at granule h*HPAD + p*4 + ((c&3) ^ ((p>>1)&3))
  // -> 8 consecutive pixels at fixed c cover all 8 bank-groups.
  __shared__ __align__(16) float xt[2 * HPAD * 4];  // 49152 B -> 3 blk/CU

  const int tid = threadIdx.x;
  const int lane = tid & 63;
  const int wv = tid >> 6;
  const int lp = lane & 31;
  const int hi2 = (lane >> 5) * 2;   // chunk offset within half from lane-half

  // XCD-bijective mapping: image b == XCD (bid&7); tl walks rows per image.
  const int bid = blockIdx.x;
  const int b  = bid & 7;
  const int tl = bid >> 3;           // 0..195
  const int tw = tl % 7, th = tl / 7;
  const int h0 = th * 8, w0 = tw * 32;

  const float qt = q[0] * q[0] * 0.1f;
  const float efv = ef[lp];
  const float wnv = winv[lp];
  const bool allfast = __all(__builtin_fabsf(efv - 1.0f) < 1e-6f);

  // ---- preload all 18 B-fragments (overlap the DMA batch)
  bf16x8 bfrag[NSTEP];
  const bf16x8* wf4 = (const bf16x8*)wfrag;
#pragma unroll
  for (int s2 = 0; s2 < NSTEP; ++s2) bfrag[s2] = wf4[s2 * 64 + lane];

  // ---- DMA staging: iters 0-5 = chunk-half 0, iters 6-11 = chunk-half 1.
  // Exactly 12 DMA per thread (pad/OOB slots pull zeros from zpool).
#pragma unroll
  for (int k = 0; k < 12; ++k) {
    const int s = k * 256 + tid;
    const int half = k >= 6;
    const int u = s - half * HPAD;         // granule within half
    float* lb = &xt[(size_t)(k * 256 + wv * 64) * 4];  // wave-uniform base
    const int uc = u < HGRAN ? u : 0;
    const int pp = uc >> 2;
    const int c  = half * 4 + ((uc & 3) ^ ((pp >> 1) & 3));
    const int rr = pp / HCOLS, cc = pp - rr * HCOLS;
    const int hh = h0 - 1 + rr, wc = w0 - 1 + cc;
    const bool live = (u < HGRAN) & ((unsigned)hh < H_) & ((unsigned)wc < W_);
    const float* src = live
        ? img + ((size_t)(b * H_ + hh) * W_ + wc) * C_ + c * 4
        : zpool + lane * 4;
    dma16(src, lb);
  }

  const int mr0 = wv * 2;  // this wave's 2 output rows (tile-relative)

  f32x16 acc0, acc1;
#pragma unroll
  for (int i = 0; i < 16; ++i) { acc0[i] = 0.f; acc1[i] = 0.f; }
  float psum[4] = {0.f, 0.f, 0.f, 0.f};

  // ---- split-wait pipeline over chunk halves
#pragma unroll
  for (int h = 0; h < 2; ++h) {
    if (h == 0) {
      // drain bfrag + half0 (all issued before half1); keep half1 in flight
      asm volatile("s_waitcnt vmcnt(6)" ::: "memory");
    } else {
      asm volatile("s_waitcnt vmcnt(0)" ::: "memory");
    }
    __builtin_amdgcn_sched_barrier(0);
    __builtin_amdgcn_s_barrier();      // all waves' half-h DMAs retired
    __builtin_amdgcn_sched_barrier(0);

    const int hbase = h * (HPAD * 4);  // float offset of half region
#pragma unroll
    for (int dx = 0; dx < 3; ++dx) {
      bf16x8 af[4];
#pragma unroll
      for (int r = 0; r < 4; ++r) {
        const int p = (mr0 + r) * HCOLS + lp + dx;
        const int pj = (p >> 1) & 3;
        const int g0 = p * 4 + (hi2 ^ pj);
        const int g1 = p * 4 + ((hi2 + 1) ^ pj);
        const float4 f0 = *(const float4*)&xt[(size_t)(hbase + g0 * 4)];
        const float4 f1 = *(const float4*)&xt[(size_t)(hbase + g1 * 4)];
        psum[r] += f0.x * f0.x + f0.y * f0.y + f0.z * f0.z + f0.w * f0.w +
                   f1.x * f1.x + f1.y * f1.y + f1.z * f1.z + f1.w * f1.w;
        bf16x8 a;
        a[0] = (bf16_t)f0.x; a[1] = (bf16_t)f0.y;
        a[2] = (bf16_t)f0.z; a[3] = (bf16_t)f0.w;
        a[4] = (bf16_t)f1.x; a[5] = (bf16_t)f1.y;
        a[6] = (bf16_t)f1.z; a[7] = (bf16_t)f1.w;
        af[r] = a;
      }
#pragma unroll
      for (int dy = 0; dy < 3; ++dy) {
        const bf16x8 bf = bfrag[2 * (dy * 3 + dx) + h];
        acc0 = __builtin_amdgcn_mfma_f32_32x32x16_bf16(af[dy],     bf, acc0, 0, 0, 0);
        acc1 = __builtin_amdgcn_mfma_f32_32x32x16_bf16(af[dy + 1], bf, acc1, 0, 0, 0);
      }
    }
  }

  // x-norm from fused sums: lane and lane^32 hold complementary 16 channels.
#pragma unroll
  for (int r = 0; r < 4; ++r) psum[r] += __shfl_xor(psum[r], 32);
  float xinv[2];
  xinv[0] = 1.f / (sqrtf(fmaxf(psum[0] + psum[1] + psum[2], 1e-12f)) + qt);
  xinv[1] = 1.f / (sqrtf(fmaxf(psum[1] + psum[2] + psum[3], 1e-12f)) + qt);

  // epilogue: C/D col = lane&31 (filter), row = (j&3)+8*(j>>2)+4*(lane>>5).
#pragma unroll
  for (int t = 0; t < 2; ++t) {
    const f32x16& acc = t ? acc1 : acc0;
    const int obase = (b * H_ + h0 + mr0 + t) * W_ + w0;
    if (allfast) {
#pragma unroll
      for (int jj = 0; jj < 16; ++jj) {
        const int row = (jj & 3) + 8 * (jj >> 2) + 4 * (lane >> 5);
        const float xi = __shfl(xinv[t], row);
        const float sim = acc[jj] * xi * wnv;
        const float r = copysignf(fabsf(sim) + 1e-12f, sim);  // |x|^1 path
        __builtin_nontemporal_store(r, &out[(size_t)(obase + row) * F_ + lp]);
      }
    } else {
#pragma unroll
      for (int jj = 0; jj < 16; ++jj) {
        const int row = (jj & 3) + 8 * (jj >> 2) + 4 * (lane >> 5);
        const float xi = __shfl(xinv[t], row);
        const float sim = acc[jj] * xi * wnv;
        const float ps = fabsf(sim) + 1e-12f;
        float r = exp2f(efv * __log2f(ps));
        r = copysignf(r, sim);
        __builtin_nontemporal_store(r, &out[(size_t)(obase + row) * F_ + lp]);
      }
    }
  }
}

// ---------------- launch ----------------------------------------------------
extern "C" void kernel_launch(void* const* d_in, const int* in_sizes, int n_in,
                              void* d_out, int out_size, void* d_ws, size_t ws_size,
                              hipStream_t stream) {
  const float* img = (const float*)d_in[0];
  const float* w   = (const float*)d_in[1];
  const float* p   = (const float*)d_in[2];
  const float* q   = (const float*)d_in[3];

  bf16_t* wfrag = (bf16_t*)d_ws;
  float*  winv  = (float*)((char*)d_ws + WFRAG_BYTES);
  float*  ef    = winv + 64;
  float*  zpool = ef + 64;   // 256 floats = 1KB zeros

  cos2d_prep<<<6, 256, 0, stream>>>(w, p, q, wfrag, winv, ef, zpool);
  // 1568 blocks: image = bid&7 (== XCD), tile-in-image = bid>>3.
  cos2d_main<<<1568, 256, 0, stream>>>(img, wfrag, winv, ef, q, zpool,
                                       (float*)d_out);
}